// Round 6
// baseline (148.496 us; speedup 1.0000x reference)
//
#include <hip/hip_runtime.h>
#include <hip/hip_bf16.h>
#include <stdint.h>

typedef __attribute__((ext_vector_type(8))) __bf16 bf16x8;
typedef __attribute__((ext_vector_type(4))) float f32x4;
typedef __attribute__((ext_vector_type(2))) float f32x2;

// Problem constants (B=1024, L=512, F=256, H=512, K=64)
#define NBATCH 1024
#define SEQL   512
#define FDIM   256
#define HDIM   512
#define KNN    64
#define NODES  65
#define ROWSTR 512           // bytes per A-tile row (256 bf16)

__device__ __forceinline__ unsigned short f32_bf16(float f) {
    unsigned int u = __float_as_uint(f);
    unsigned int r = u + 0x7FFFu + ((u >> 16) & 1u);
    return (unsigned short)(r >> 16);
}

// ---------------------------------------------------------------------------
// Kernel 1: convert W1r/W1l to bf16 in MFMA-fragment-major layout (round-3,
// validated): chunk t = ((mat*32 + cb16)*8 + kidx)*64 + lane, 16 B per chunk.
// A wave's B-fragment load is then one contiguous 1KB segment.
// ---------------------------------------------------------------------------
__global__ __launch_bounds__(256) void convw_kernel(
    const float* __restrict__ W1r, const float* __restrict__ W1l,
    unsigned short* __restrict__ Wb)
{
    int i = blockIdx.x * 256 + threadIdx.x;   // 0..32767, one 16B output chunk
    int f = i * 8;                            // first source float in [W1r;W1l]
    int row = f >> 8;                         // 0..1023 (concat row)
    int col = f & 255;                        // multiple of 8
    int mat = row >> 9;
    int r   = row & 511;
    int j   = col >> 3;                       // 0..31
    int g   = j & 3, kidx = j >> 2;
    int cl  = r & 15, cb16 = r >> 4;
    int lane = g * 16 + cl;

    const float* src = (mat ? W1l : W1r) + (size_t)r * FDIM + col;
    float4 a = *reinterpret_cast<const float4*>(src);
    float4 c = *reinterpret_cast<const float4*>(src + 4);
    uint4 t;
    t.x = (unsigned)f32_bf16(a.x) | ((unsigned)f32_bf16(a.y) << 16);
    t.y = (unsigned)f32_bf16(a.z) | ((unsigned)f32_bf16(a.w) << 16);
    t.z = (unsigned)f32_bf16(c.x) | ((unsigned)f32_bf16(c.y) << 16);
    t.w = (unsigned)f32_bf16(c.z) | ((unsigned)f32_bf16(c.w) << 16);

    size_t tchunk = (size_t)((mat * 32 + cb16) * 8 + kidx) * 64 + lane;
    *reinterpret_cast<uint4*>(Wb + tchunk * 8) = t;
}

// ---------------------------------------------------------------------------
// Kernel 2: 256-thread block per batch, 4 blocks/CU, all 1024 resident.
// Same bitonic network (2 keys/thread, slot-major: slot0=elems 0..255,
// slot1=256..511; j=256 thread-local, j in {64,128} via LDS, j<=32 shuffle).
// Same gather (16 rows/thread) and same GEMM inner loop (4 passes of 32).
// ---------------------------------------------------------------------------
__global__ __launch_bounds__(256, 4) void fused_kernel(
    const float* __restrict__ inputs,   // [B,L,F]
    const float* __restrict__ coords,   // [B,L,2]
    const float* __restrict__ targets,  // [B,L,1]
    const int*   __restrict__ lens,     // [B]
    const unsigned short* __restrict__ Wb, // fragment-major, 512 KiB
    const float* __restrict__ b1,       // [H]
    const float* __restrict__ W2l,      // [H]
    const float* __restrict__ W2r,      // [H]
    const float* __restrict__ b2,       // [1]
    float* __restrict__ dout)           // [2048]
{
    __shared__ __align__(16) unsigned short ldsA[66 * FDIM];  // 33 KiB, swizzled
    __shared__ __align__(16) unsigned char uni[4096];         // keys / part union
    __shared__ int idxs[KNN];

    const int b    = blockIdx.x;
    const int tid  = threadIdx.x;       // 0..255
    const int lane = tid & 63;

    const float* cb = coords + (size_t)b * (SEQL * 2);
    const float qx = cb[0], qy = cb[1];
    const int len = lens[b];

    // ---- phase 1: dual keys (elems tid and tid+256) + bitonic sort ----
    unsigned long long* keys = reinterpret_cast<unsigned long long*>(uni); // [512]
    unsigned long long k0 = ~0ull, k1 = ~0ull;
    if (tid < SEQL - 1 && tid < len - 1) {
        f32x2 c2 = __builtin_nontemporal_load(
            reinterpret_cast<const f32x2*>(cb + 2 * (tid + 1)));
        float dx = c2[0] - qx, dy = c2[1] - qy;
        float d2 = dx * dx + dy * dy;
        k0 = ((unsigned long long)__float_as_uint(d2) << 32) | (unsigned int)tid;
    }
    {
        int c1 = tid + 256;
        if (c1 < SEQL - 1 && c1 < len - 1) {
            f32x2 c2 = __builtin_nontemporal_load(
                reinterpret_cast<const f32x2*>(cb + 2 * (c1 + 1)));
            float dx = c2[0] - qx, dy = c2[1] - qy;
            float d2 = dx * dx + dy * dy;
            k1 = ((unsigned long long)__float_as_uint(d2) << 32) | (unsigned int)c1;
        }
    }

    for (int k = 2; k <= 512; k <<= 1) {
        for (int j = k >> 1; j >= 1; j >>= 1) {
            if (j == 256) {
                // k==512 only: partner is the other slot of this thread;
                // dir ascending for both -> slot0 keeps min.
                unsigned long long lo = (k0 < k1) ? k0 : k1;
                unsigned long long hi = (k0 < k1) ? k1 : k0;
                k0 = lo; k1 = hi;
            } else if (j >= 64) {                 // cross-wave via LDS
                keys[tid] = k0; keys[tid + 256] = k1;
                __syncthreads();
                unsigned long long o0 = keys[tid ^ j];
                unsigned long long o1 = keys[(tid ^ j) + 256];
                bool t0 = (((tid & j) == 0) == ((tid & k) == 0));
                bool t1 = (((tid & j) == 0) == (((tid + 256) & k) == 0));
                k0 = (t0 == (k0 < o0)) ? k0 : o0;
                k1 = (t1 == (k1 < o1)) ? k1 : o1;
                __syncthreads();
            } else {                               // in-wave shuffle
                unsigned long long o0 = __shfl_xor(k0, j, 64);
                unsigned long long o1 = __shfl_xor(k1, j, 64);
                bool t0 = (((tid & j) == 0) == ((tid & k) == 0));
                bool t1 = (((tid & j) == 0) == (((tid + 256) & k) == 0));
                k0 = (t0 == (k0 < o0)) ? k0 : o0;
                k1 = (t1 == (k1 < o1)) ? k1 : o1;
            }
        }
    }

    // ranks 0..63 live at threads 0..63, slot 0
    if (tid < KNN) idxs[tid] = (int)(unsigned int)(k0 & 0xffffffffull);
    if (tid == 0) {
        dout[b] = b2[0];                                  // bias init; epilogue accumulates
        dout[NBATCH + b] = targets[(size_t)b * SEQL];     // y head
    }
    __syncthreads();

    const int c4 = tid & 63;          // float4 column 0..63
    const int g0 = tid >> 6;          // row phase 0..3

#define STROW(row, v) do {                                                     \
    int off_ = (row) * ROWSTR + c4 * 8; off_ ^= ((row) & 7) << 4;              \
    uint2 pk_;                                                                 \
    pk_.x = (unsigned)f32_bf16((v)[0]) | ((unsigned)f32_bf16((v)[1]) << 16);   \
    pk_.y = (unsigned)f32_bf16((v)[2]) | ((unsigned)f32_bf16((v)[3]) << 16);   \
    *reinterpret_cast<uint2*>(reinterpret_cast<char*>(ldsA) + off_) = pk_;     \
} while (0)

    // ---- phase 2: nt gather, rows r = g0+4q (+row 64 by g0==0), 8-deep ILP --
    {
        const float* xb = inputs + (size_t)b * SEQL * FDIM + c4 * 4;
        float4 sum = {0.f, 0.f, 0.f, 0.f};
        #pragma unroll 1
        for (int half = 0; half < 2; ++half) {
            int srcs[8];
            #pragma unroll
            for (int q = 0; q < 8; ++q) {
                int r = g0 + (half * 8 + q) * 4;
                srcs[q] = (r == 0) ? 0 : idxs[r - 1];
            }
            f32x4 v[8];
            #pragma unroll
            for (int q = 0; q < 8; ++q)
                v[q] = __builtin_nontemporal_load(
                    reinterpret_cast<const f32x4*>(xb + (size_t)srcs[q] * FDIM));
            #pragma unroll
            for (int q = 0; q < 8; ++q) {
                int r = g0 + (half * 8 + q) * 4;
                sum.x += v[q][0]; sum.y += v[q][1];
                sum.z += v[q][2]; sum.w += v[q][3];
                STROW(r, v[q]);
            }
        }
        if (g0 == 0) {
            f32x4 v8 = __builtin_nontemporal_load(
                reinterpret_cast<const f32x4*>(xb + (size_t)idxs[63] * FDIM));
            sum.x += v8[0]; sum.y += v8[1]; sum.z += v8[2]; sum.w += v8[3];
            STROW(64, v8);
        }
        __syncthreads();                      // keys lifetime over before part write
        float4* part = reinterpret_cast<float4*>(uni);    // [4][64]
        part[g0 * 64 + c4] = sum;
    }
    __syncthreads();
    if (tid < 64) {                              // row 65 = aggr1 (bf16)
        const float4* part = reinterpret_cast<const float4*>(uni);
        float sx = 0.f, sy = 0.f, sz = 0.f, sw = 0.f;
        #pragma unroll
        for (int q = 0; q < 4; ++q) {
            float4 p = part[q * 64 + tid];
            sx += p.x; sy += p.y; sz += p.z; sw += p.w;
        }
        const float inv = 1.0f / 65.0f;
        uint2 pk;
        pk.x = (unsigned)f32_bf16(sx * inv) | ((unsigned)f32_bf16(sy * inv) << 16);
        pk.y = (unsigned)f32_bf16(sz * inv) | ((unsigned)f32_bf16(sw * inv) << 16);
        int off = 65 * ROWSTR + tid * 8; off ^= 0x10;     // (65&7)<<4
        *reinterpret_cast<uint2*>(reinterpret_cast<char*>(ldsA) + off) = pk;
    }
    __syncthreads();
#undef STROW

    // ---- phase 3: GEMM + epilogue, per wave over 4 passes of 32 cols ----
    const int w  = tid >> 6;          // wave 0..3
    const int cl = lane & 15, g = lane >> 4;

    #pragma unroll 1
    for (int p = 0; p < 4; ++p) {
        const int cbase = w * 128 + p * 32;

        f32x4 acc[5][2], accU[2];
        #pragma unroll
        for (int m = 0; m < 5; ++m) {
            acc[m][0] = f32x4{0.f, 0.f, 0.f, 0.f};
            acc[m][1] = f32x4{0.f, 0.f, 0.f, 0.f};
        }
        accU[0] = f32x4{0.f, 0.f, 0.f, 0.f};
        accU[1] = f32x4{0.f, 0.f, 0.f, 0.f};

        // fragment-major B: block index blkR = cbase/16; W1l at block +32.
        const int blkR = w * 8 + p * 2;
        const char* base = (const char*)Wb;
        const size_t oR0 = (size_t)(blkR * 8) * 1024 + (size_t)lane * 16;
        const size_t oR1 = oR0 + 8 * 1024;
        const size_t oL0 = oR0 + (size_t)32 * 8 * 1024;
        const size_t oL1 = oL0 + 8 * 1024;

        #pragma unroll
        for (int kc = 0; kc < 4; ++kc) {
            #pragma unroll
            for (int s = 0; s < 2; ++s) {
                const int kb  = kc * 128 + s * 64;        // byte offset of k-slice (A)
                const int kfr = (kc * 2 + s) * 1024;      // fragment-major B offset
                bf16x8 bR[2], bL[2], aF[5];
                bR[0] = *reinterpret_cast<const bf16x8*>(base + oR0 + kfr);
                bR[1] = *reinterpret_cast<const bf16x8*>(base + oR1 + kfr);
                bL[0] = *reinterpret_cast<const bf16x8*>(base + oL0 + kfr);
                bL[1] = *reinterpret_cast<const bf16x8*>(base + oL1 + kfr);
                #pragma unroll
                for (int m = 0; m < 5; ++m) {
                    int row = m * 16 + cl;
                    int off = row * ROWSTR + kb + g * 16;
                    off ^= (row & 7) << 4;
                    aF[m] = *reinterpret_cast<const bf16x8*>(
                        reinterpret_cast<const char*>(ldsA) + off);
                }
                #pragma unroll
                for (int m = 0; m < 5; ++m) {
                    acc[m][0] = __builtin_amdgcn_mfma_f32_16x16x32_bf16(
                        aF[m], bR[0], acc[m][0], 0, 0, 0);
                    acc[m][1] = __builtin_amdgcn_mfma_f32_16x16x32_bf16(
                        aF[m], bR[1], acc[m][1], 0, 0, 0);
                }
                accU[0] = __builtin_amdgcn_mfma_f32_16x16x32_bf16(
                    aF[4], bL[0], accU[0], 0, 0, 0);
                accU[1] = __builtin_amdgcn_mfma_f32_16x16x32_bf16(
                    aF[4], bL[1], accU[1], 0, 0, 0);
            }
        }

        // epilogue (C/D: col=lane&15, row=(lane>>4)*4+reg)
        float contrib = 0.f;
        #pragma unroll
        for (int nf = 0; nf < 2; ++nf) {
            int c = cbase + nf * 16 + cl;
            float wl  = W2l[c] * (1.0f / 65.0f);
            float w2  = W2r[c];
            float uc  = __shfl(accU[nf][1], cl, 64) + b1[c];   // A-row 65 -> C-row 1
            float ps = 0.f;
            #pragma unroll
            for (int m = 0; m < 4; ++m)
                #pragma unroll
                for (int v = 0; v < 4; ++v)
                    ps += fmaxf(acc[m][nf][v] + uc, 0.f);      // rows 0..63
            {
                float hh = fmaxf(acc[4][nf][0] + uc, 0.f);     // row 64 (g==0,v==0 only)
                ps += (g == 0) ? hh : 0.f;
            }
            contrib += wl * ps;
            if (g == 0) {                                       // j==0 head term (row 0)
                float h0 = fmaxf(acc[0][nf][0] + uc, 0.f);
                contrib += w2 * h0;
            }
        }
        #pragma unroll
        for (int mask = 1; mask < 64; mask <<= 1)
            contrib += __shfl_xor(contrib, mask, 64);
        if (lane == 0) atomicAdd(&dout[b], contrib);
    }
}

// ---------------------------------------------------------------------------
extern "C" void kernel_launch(void* const* d_in, const int* in_sizes, int n_in,
                              void* d_out, int out_size, void* d_ws, size_t ws_size,
                              hipStream_t stream) {
    const float* inputs  = (const float*)d_in[0];
    const float* coords  = (const float*)d_in[1];
    const float* targets = (const float*)d_in[2];
    const int*   lens    = (const int*)d_in[3];
    const float* W1l     = (const float*)d_in[4];
    const float* W1r     = (const float*)d_in[5];
    const float* b1      = (const float*)d_in[6];
    const float* W2l     = (const float*)d_in[7];
    const float* W2r     = (const float*)d_in[8];
    const float* b2      = (const float*)d_in[9];
    float* dout = (float*)d_out;

    unsigned short* Wb = (unsigned short*)d_ws;   // 512 KiB, fragment-major

    convw_kernel<<<dim3(2 * HDIM * FDIM / (256 * 8)), dim3(256), 0, stream>>>(
        W1r, W1l, Wb);

    fused_kernel<<<dim3(NBATCH), dim3(256), 0, stream>>>(
        inputs, coords, targets, lens, Wb, b1, W2l, W2r, b2, dout);
}

// Round 8
// 74.922 us; speedup vs baseline: 1.9820x; 1.9820x over previous
//
#include <hip/hip_runtime.h>
#include <hip/hip_bf16.h>
#include <stdint.h>

typedef __attribute__((ext_vector_type(8))) __bf16 bf16x8;
typedef __attribute__((ext_vector_type(4))) float f32x4;
typedef __attribute__((ext_vector_type(2))) float f32x2;
typedef __attribute__((ext_vector_type(4))) unsigned int u32x4;

// Problem constants (B=1024, L=512, F=256, H=512, K=64)
#define NBATCH 1024
#define SEQL   512
#define FDIM   256
#define HDIM   512
#define KNN    64
#define NODES  65
#define ROWSTR 512               // bytes per A-tile row (256 bf16)
#define TILE_SHORTS 16896        // 66*FDIM shorts = 33,792 B per tile
#define TILE_U4     2112         // uint4 per tile

__device__ __forceinline__ unsigned short f32_bf16(float f) {
    unsigned int u = __float_as_uint(f);
    unsigned int r = u + 0x7FFFu + ((u >> 16) & 1u);
    return (unsigned short)(r >> 16);
}

// ---------------------------------------------------------------------------
// Kernel 1: convert W1r/W1l to bf16 in MFMA-fragment-major layout (round-3,
// validated): chunk t = ((mat*32 + cb16)*8 + kidx)*64 + lane, 16 B per chunk.
// A wave's B-fragment load is then one contiguous 1KB segment.
// ---------------------------------------------------------------------------
__global__ __launch_bounds__(256) void convw_kernel(
    const float* __restrict__ W1r, const float* __restrict__ W1l,
    unsigned short* __restrict__ Wb)
{
    int i = blockIdx.x * 256 + threadIdx.x;   // 0..32767, one 16B output chunk
    int f = i * 8;                            // first source float in [W1r;W1l]
    int row = f >> 8;                         // 0..1023 (concat row)
    int col = f & 255;                        // multiple of 8
    int mat = row >> 9;
    int r   = row & 511;
    int j   = col >> 3;                       // 0..31
    int g   = j & 3, kidx = j >> 2;
    int cl  = r & 15, cb16 = r >> 4;
    int lane = g * 16 + cl;

    const float* src = (mat ? W1l : W1r) + (size_t)r * FDIM + col;
    float4 a = *reinterpret_cast<const float4*>(src);
    float4 c = *reinterpret_cast<const float4*>(src + 4);
    uint4 t;
    t.x = (unsigned)f32_bf16(a.x) | ((unsigned)f32_bf16(a.y) << 16);
    t.y = (unsigned)f32_bf16(a.z) | ((unsigned)f32_bf16(a.w) << 16);
    t.z = (unsigned)f32_bf16(c.x) | ((unsigned)f32_bf16(c.y) << 16);
    t.w = (unsigned)f32_bf16(c.z) | ((unsigned)f32_bf16(c.w) << 16);

    size_t tchunk = (size_t)((mat * 32 + cb16) * 8 + kidx) * 64 + lane;
    *reinterpret_cast<uint4*>(Wb + tchunk * 8) = t;
}

// ---------------------------------------------------------------------------
// Kernel A (split path): champion phases 1+2 verbatim (sort + gather into the
// swizzled bf16 LDS A-tile), then dump the 33 KB tile to workspace.
// 37.3 KB LDS + 64-VGPR target -> 4 blocks/CU, 32 waves, single generation.
// aggr1 reduction uses a two-pass 4 KB buffer (aliasing keys) preserving the
// champion's exact left-to-right summation order -> bit-identical tile.
// ---------------------------------------------------------------------------
__global__ __launch_bounds__(512, 8) void knn_gather_kernel(
    const float* __restrict__ inputs,   // [B,L,F]
    const float* __restrict__ coords,   // [B,L,2]
    const int*   __restrict__ lens,     // [B]
    unsigned short* __restrict__ tiles) // [B][TILE_SHORTS]
{
    __shared__ __align__(16) unsigned long long keys[512];    // 4 KiB (↔ part4)
    __shared__ int idxs[KNN];
    __shared__ __align__(16) unsigned short ldsA[66 * FDIM];  // 33 KiB, swizzled

    const int b   = blockIdx.x;
    const int tid = threadIdx.x;
    const float* cb = coords + (size_t)b * (SEQL * 2);
    const float qx = cb[0], qy = cb[1];
    const int len = lens[b];

    // ---- phase 1: keys + bitonic sort (ascending) — champion verbatim ----
    unsigned long long key;
    if (tid < SEQL - 1 && tid < len - 1) {
        f32x2 c2 = __builtin_nontemporal_load(
            reinterpret_cast<const f32x2*>(cb + 2 * (tid + 1)));
        float dx = c2[0] - qx;
        float dy = c2[1] - qy;
        float d2 = dx * dx + dy * dy;
        key = ((unsigned long long)__float_as_uint(d2) << 32) | (unsigned int)tid;
    } else {
        key = ~0ull;
    }

    for (int k = 2; k <= 512; k <<= 1) {
        for (int j = k >> 1; j >= 64; j >>= 1) {          // cross-wave via LDS
            keys[tid] = key;
            __syncthreads();
            unsigned long long other = keys[tid ^ j];
            bool takemin = (((tid & j) == 0) == ((tid & k) == 0));
            key = (takemin == (key < other)) ? key : other;
            __syncthreads();
        }
        for (int j = ((k >> 1) > 32 ? 32 : (k >> 1)); j >= 1; j >>= 1) {  // in-wave
            unsigned long long other = __shfl_xor(key, j, 64);
            bool takemin = (((tid & j) == 0) == ((tid & k) == 0));
            key = (takemin == (key < other)) ? key : other;
        }
    }

    if (tid < KNN) idxs[tid] = (int)(unsigned int)(key & 0xffffffffull);
    __syncthreads();

    const int c4 = tid & 63;          // float4 column 0..63
    const int g0 = tid >> 6;          // row phase 0..7

#define STROW(row, v) do {                                                     \
    int off_ = (row) * ROWSTR + c4 * 8; off_ ^= ((row) & 7) << 4;              \
    uint2 pk_;                                                                 \
    pk_.x = (unsigned)f32_bf16((v)[0]) | ((unsigned)f32_bf16((v)[1]) << 16);   \
    pk_.y = (unsigned)f32_bf16((v)[2]) | ((unsigned)f32_bf16((v)[3]) << 16);   \
    *reinterpret_cast<uint2*>(reinterpret_cast<char*>(ldsA) + off_) = pk_;     \
} while (0)

    // ---- phase 2: nt gather, rows r = g0+8q (+row 64 by g0==0), 4-deep ILP --
    float4 sum = {0.f, 0.f, 0.f, 0.f};
    {
        const float* xb = inputs + (size_t)b * SEQL * FDIM + c4 * 4;
        #pragma unroll 1
        for (int kk = 0; kk < 8; kk += 4) {
            int srcs[4];
            #pragma unroll
            for (int q = 0; q < 4; ++q) {
                int r = g0 + (kk + q) * 8;
                srcs[q] = (r == 0) ? 0 : idxs[r - 1];
            }
            f32x4 v[4];
            #pragma unroll
            for (int q = 0; q < 4; ++q)
                v[q] = __builtin_nontemporal_load(
                    reinterpret_cast<const f32x4*>(xb + (size_t)srcs[q] * FDIM));
            #pragma unroll
            for (int q = 0; q < 4; ++q) {
                int r = g0 + (kk + q) * 8;
                sum.x += v[q][0]; sum.y += v[q][1];
                sum.z += v[q][2]; sum.w += v[q][3];
                STROW(r, v[q]);
            }
        }
        if (g0 == 0) {
            f32x4 v8 = __builtin_nontemporal_load(
                reinterpret_cast<const f32x4*>(xb + (size_t)idxs[63] * FDIM));
            sum.x += v8[0]; sum.y += v8[1]; sum.z += v8[2]; sum.w += v8[3];
            STROW(64, v8);
        }
    }

    // ---- aggr1 reduce (exact champion order p0+p1+...+p7) via 4 KB buffer --
    float4* part4 = reinterpret_cast<float4*>(keys);          // aliases keys
    __syncthreads();                      // sort reads of keys complete
    if (g0 < 4) part4[g0 * 64 + c4] = *reinterpret_cast<float4*>(&sum);
    __syncthreads();
    float sx = 0.f, sy = 0.f, sz = 0.f, sw = 0.f;
    if (tid < 64) {
        #pragma unroll
        for (int q = 0; q < 4; ++q) {
            float4 p = part4[q * 64 + tid];
            sx += p.x; sy += p.y; sz += p.z; sw += p.w;
        }
    }
    __syncthreads();
    if (g0 >= 4) part4[(g0 - 4) * 64 + c4] = *reinterpret_cast<float4*>(&sum);
    __syncthreads();
    if (tid < 64) {
        #pragma unroll
        for (int q = 0; q < 4; ++q) {
            float4 p = part4[q * 64 + tid];
            sx += p.x; sy += p.y; sz += p.z; sw += p.w;
        }
        const float inv = 1.0f / 65.0f;
        uint2 pk;
        pk.x = (unsigned)f32_bf16(sx * inv) | ((unsigned)f32_bf16(sy * inv) << 16);
        pk.y = (unsigned)f32_bf16(sz * inv) | ((unsigned)f32_bf16(sw * inv) << 16);
        int off = 65 * ROWSTR + tid * 8; off ^= 0x10;         // (65&7)<<4
        *reinterpret_cast<uint2*>(reinterpret_cast<char*>(ldsA) + off) = pk;
    }
    __syncthreads();
#undef STROW

    // ---- dump tile to workspace (coalesced) ----
    const u32x4* src = reinterpret_cast<const u32x4*>(ldsA);
    u32x4* dst = reinterpret_cast<u32x4*>(tiles + (size_t)b * TILE_SHORTS);
    for (int i = tid; i < TILE_U4; i += 512)
        __builtin_nontemporal_store(src[i], dst + i);
}

// ---------------------------------------------------------------------------
// Kernel B (split path): load tile -> LDS, then champion GEMM + epilogue
// verbatim. ldsA declared 80 rows so the m==4 fragment reads (rows 64..79)
// stay inside this kernel's own LDS allocation (garbage rows discarded).
// ---------------------------------------------------------------------------
__global__ __launch_bounds__(512, 4) void gemm_kernel(
    const unsigned short* __restrict__ tiles, // [B][TILE_SHORTS]
    const unsigned short* __restrict__ Wb,    // fragment-major, 512 KiB
    const float* __restrict__ b1,       // [H]
    const float* __restrict__ W2l,      // [H]
    const float* __restrict__ W2r,      // [H]
    const float* __restrict__ b2,       // [1]
    const float* __restrict__ targets,  // [B,L,1]
    float* __restrict__ dout)           // [2048]
{
    __shared__ __align__(16) unsigned short ldsA[80 * FDIM];  // 40 KiB

    const int b   = blockIdx.x;
    const int tid = threadIdx.x;

    if (tid == 0) {
        dout[b] = b2[0];                                  // bias init; epilogue accumulates
        dout[NBATCH + b] = targets[(size_t)b * SEQL];     // y head
    }
    {
        const u32x4* src = reinterpret_cast<const u32x4*>(
            tiles + (size_t)b * TILE_SHORTS);
        u32x4* dst = reinterpret_cast<u32x4*>(ldsA);
        for (int i = tid; i < TILE_U4; i += 512)
            dst[i] = __builtin_nontemporal_load(src + i);
    }
    __syncthreads();

    // ---- GEMM + epilogue, per wave over 2 passes of 32 cols — verbatim ----
    const int lane = tid & 63;
    const int w    = tid >> 6;
    const int cl   = lane & 15, g = lane >> 4;

    #pragma unroll
    for (int p = 0; p < 2; ++p) {
        const int cbase = w * 64 + p * 32;

        f32x4 acc[5][2], accU[2];
        #pragma unroll
        for (int m = 0; m < 5; ++m) {
            acc[m][0] = f32x4{0.f, 0.f, 0.f, 0.f};
            acc[m][1] = f32x4{0.f, 0.f, 0.f, 0.f};
        }
        accU[0] = f32x4{0.f, 0.f, 0.f, 0.f};
        accU[1] = f32x4{0.f, 0.f, 0.f, 0.f};

        const int blkR = w * 4 + p * 2;
        const char* base = (const char*)Wb;
        const size_t oR0 = (size_t)(blkR * 8) * 1024 + (size_t)lane * 16;
        const size_t oR1 = oR0 + 8 * 1024;
        const size_t oL0 = oR0 + (size_t)32 * 8 * 1024;
        const size_t oL1 = oL0 + 8 * 1024;

        #pragma unroll
        for (int kc = 0; kc < 4; ++kc) {
            #pragma unroll
            for (int s = 0; s < 2; ++s) {
                const int kb  = kc * 128 + s * 64;        // byte offset of k-slice (A)
                const int kfr = (kc * 2 + s) * 1024;      // fragment-major B offset
                bf16x8 bR[2], bL[2], aF[5];
                bR[0] = *reinterpret_cast<const bf16x8*>(base + oR0 + kfr);
                bR[1] = *reinterpret_cast<const bf16x8*>(base + oR1 + kfr);
                bL[0] = *reinterpret_cast<const bf16x8*>(base + oL0 + kfr);
                bL[1] = *reinterpret_cast<const bf16x8*>(base + oL1 + kfr);
                #pragma unroll
                for (int m = 0; m < 5; ++m) {
                    int row = m * 16 + cl;
                    int off = row * ROWSTR + kb + g * 16;
                    off ^= (row & 7) << 4;
                    aF[m] = *reinterpret_cast<const bf16x8*>(
                        reinterpret_cast<const char*>(ldsA) + off);
                }
                #pragma unroll
                for (int m = 0; m < 5; ++m) {
                    acc[m][0] = __builtin_amdgcn_mfma_f32_16x16x32_bf16(
                        aF[m], bR[0], acc[m][0], 0, 0, 0);
                    acc[m][1] = __builtin_amdgcn_mfma_f32_16x16x32_bf16(
                        aF[m], bR[1], acc[m][1], 0, 0, 0);
                }
                accU[0] = __builtin_amdgcn_mfma_f32_16x16x32_bf16(
                    aF[4], bL[0], accU[0], 0, 0, 0);
                accU[1] = __builtin_amdgcn_mfma_f32_16x16x32_bf16(
                    aF[4], bL[1], accU[1], 0, 0, 0);
            }
        }

        float contrib = 0.f;
        #pragma unroll
        for (int nf = 0; nf < 2; ++nf) {
            int c = cbase + nf * 16 + cl;
            float wl  = W2l[c] * (1.0f / 65.0f);
            float w2  = W2r[c];
            float uc  = __shfl(accU[nf][1], cl, 64) + b1[c];   // A-row 65 -> C-row 1
            float ps = 0.f;
            #pragma unroll
            for (int m = 0; m < 4; ++m)
                #pragma unroll
                for (int v = 0; v < 4; ++v)
                    ps += fmaxf(acc[m][nf][v] + uc, 0.f);      // rows 0..63
            {
                float hh = fmaxf(acc[4][nf][0] + uc, 0.f);     // row 64 (g==0,v==0 only)
                ps += (g == 0) ? hh : 0.f;
            }
            contrib += wl * ps;
            if (g == 0) {                                       // j==0 head term (row 0)
                float h0 = fmaxf(acc[0][nf][0] + uc, 0.f);
                contrib += w2 * h0;
            }
        }
        #pragma unroll
        for (int mask = 1; mask < 64; mask <<= 1)
            contrib += __shfl_xor(contrib, mask, 64);
        if (lane == 0) atomicAdd(&dout[b], contrib);
    }
}

// ---------------------------------------------------------------------------
// Fallback: round-5 champion fused kernel (verbatim), used if ws too small.
// ---------------------------------------------------------------------------
__global__ __launch_bounds__(512, 4) void fused_kernel(
    const float* __restrict__ inputs, const float* __restrict__ coords,
    const float* __restrict__ targets, const int* __restrict__ lens,
    const unsigned short* __restrict__ Wb, const float* __restrict__ b1,
    const float* __restrict__ W2l, const float* __restrict__ W2r,
    const float* __restrict__ b2, float* __restrict__ dout)
{
    __shared__ unsigned long long keys[512];
    __shared__ int idxs[KNN];
    __shared__ __align__(16) float4 part[8][64];
    __shared__ __align__(16) unsigned short ldsA[66 * FDIM];

    const int b   = blockIdx.x;
    const int tid = threadIdx.x;
    const float* cb = coords + (size_t)b * (SEQL * 2);
    const float qx = cb[0], qy = cb[1];
    const int len = lens[b];

    unsigned long long key;
    if (tid < SEQL - 1 && tid < len - 1) {
        f32x2 c2 = __builtin_nontemporal_load(
            reinterpret_cast<const f32x2*>(cb + 2 * (tid + 1)));
        float dx = c2[0] - qx;
        float dy = c2[1] - qy;
        float d2 = dx * dx + dy * dy;
        key = ((unsigned long long)__float_as_uint(d2) << 32) | (unsigned int)tid;
    } else {
        key = ~0ull;
    }

    for (int k = 2; k <= 512; k <<= 1) {
        for (int j = k >> 1; j >= 64; j >>= 1) {
            keys[tid] = key;
            __syncthreads();
            unsigned long long other = keys[tid ^ j];
            bool takemin = (((tid & j) == 0) == ((tid & k) == 0));
            key = (takemin == (key < other)) ? key : other;
            __syncthreads();
        }
        for (int j = ((k >> 1) > 32 ? 32 : (k >> 1)); j >= 1; j >>= 1) {
            unsigned long long other = __shfl_xor(key, j, 64);
            bool takemin = (((tid & j) == 0) == ((tid & k) == 0));
            key = (takemin == (key < other)) ? key : other;
        }
    }

    if (tid < KNN) idxs[tid] = (int)(unsigned int)(key & 0xffffffffull);
    if (tid == 0) {
        dout[b] = b2[0];
        dout[NBATCH + b] = targets[(size_t)b * SEQL];
    }
    __syncthreads();

    const int c4 = tid & 63;
    const int g0 = tid >> 6;

#define STROW(row, v) do {                                                     \
    int off_ = (row) * ROWSTR + c4 * 8; off_ ^= ((row) & 7) << 4;              \
    uint2 pk_;                                                                 \
    pk_.x = (unsigned)f32_bf16((v)[0]) | ((unsigned)f32_bf16((v)[1]) << 16);   \
    pk_.y = (unsigned)f32_bf16((v)[2]) | ((unsigned)f32_bf16((v)[3]) << 16);   \
    *reinterpret_cast<uint2*>(reinterpret_cast<char*>(ldsA) + off_) = pk_;     \
} while (0)

    {
        const float* xb = inputs + (size_t)b * SEQL * FDIM + c4 * 4;
        int srcs[8];
        #pragma unroll
        for (int q = 0; q < 8; ++q) {
            int r = g0 + q * 8;
            srcs[q] = (r == 0) ? 0 : idxs[r - 1];
        }
        int src8 = idxs[63];
        f32x4 v[8];
        #pragma unroll
        for (int q = 0; q < 8; ++q)
            v[q] = __builtin_nontemporal_load(
                reinterpret_cast<const f32x4*>(xb + (size_t)srcs[q] * FDIM));
        f32x4 v8;
        if (g0 == 0)
            v8 = __builtin_nontemporal_load(
                reinterpret_cast<const f32x4*>(xb + (size_t)src8 * FDIM));

        float4 sum = {0.f, 0.f, 0.f, 0.f};
        #pragma unroll
        for (int q = 0; q < 8; ++q) {
            int r = g0 + q * 8;
            sum.x += v[q][0]; sum.y += v[q][1]; sum.z += v[q][2]; sum.w += v[q][3];
            STROW(r, v[q]);
        }
        if (g0 == 0) {
            sum.x += v8[0]; sum.y += v8[1]; sum.z += v8[2]; sum.w += v8[3];
            STROW(64, v8);
        }
        part[g0][c4] = sum;
    }
    __syncthreads();
    if (tid < 64) {
        float sx = 0.f, sy = 0.f, sz = 0.f, sw = 0.f;
        #pragma unroll
        for (int q = 0; q < 8; ++q) {
            float4 p = part[q][tid];
            sx += p.x; sy += p.y; sz += p.z; sw += p.w;
        }
        const float inv = 1.0f / 65.0f;
        uint2 pk;
        pk.x = (unsigned)f32_bf16(sx * inv) | ((unsigned)f32_bf16(sy * inv) << 16);
        pk.y = (unsigned)f32_bf16(sz * inv) | ((unsigned)f32_bf16(sw * inv) << 16);
        int off = 65 * ROWSTR + tid * 8; off ^= 0x10;
        *reinterpret_cast<uint2*>(reinterpret_cast<char*>(ldsA) + off) = pk;
    }
    __syncthreads();
#undef STROW

    const int lane = tid & 63;
    const int w    = tid >> 6;
    const int cl   = lane & 15, g = lane >> 4;

    #pragma unroll
    for (int p = 0; p < 2; ++p) {
        const int cbase = w * 64 + p * 32;

        f32x4 acc[5][2], accU[2];
        #pragma unroll
        for (int m = 0; m < 5; ++m) {
            acc[m][0] = f32x4{0.f, 0.f, 0.f, 0.f};
            acc[m][1] = f32x4{0.f, 0.f, 0.f, 0.f};
        }
        accU[0] = f32x4{0.f, 0.f, 0.f, 0.f};
        accU[1] = f32x4{0.f, 0.f, 0.f, 0.f};

        const int blkR = w * 4 + p * 2;
        const char* base = (const char*)Wb;
        const size_t oR0 = (size_t)(blkR * 8) * 1024 + (size_t)lane * 16;
        const size_t oR1 = oR0 + 8 * 1024;
        const size_t oL0 = oR0 + (size_t)32 * 8 * 1024;
        const size_t oL1 = oL0 + 8 * 1024;

        #pragma unroll
        for (int kc = 0; kc < 4; ++kc) {
            #pragma unroll
            for (int s = 0; s < 2; ++s) {
                const int kb  = kc * 128 + s * 64;
                const int kfr = (kc * 2 + s) * 1024;
                bf16x8 bR[2], bL[2], aF[5];
                bR[0] = *reinterpret_cast<const bf16x8*>(base + oR0 + kfr);
                bR[1] = *reinterpret_cast<const bf16x8*>(base + oR1 + kfr);
                bL[0] = *reinterpret_cast<const bf16x8*>(base + oL0 + kfr);
                bL[1] = *reinterpret_cast<const bf16x8*>(base + oL1 + kfr);
                #pragma unroll
                for (int m = 0; m < 5; ++m) {
                    int row = m * 16 + cl;
                    int off = row * ROWSTR + kb + g * 16;
                    off ^= (row & 7) << 4;
                    aF[m] = *reinterpret_cast<const bf16x8*>(
                        reinterpret_cast<const char*>(ldsA) + off);
                }
                #pragma unroll
                for (int m = 0; m < 5; ++m) {
                    acc[m][0] = __builtin_amdgcn_mfma_f32_16x16x32_bf16(
                        aF[m], bR[0], acc[m][0], 0, 0, 0);
                    acc[m][1] = __builtin_amdgcn_mfma_f32_16x16x32_bf16(
                        aF[m], bR[1], acc[m][1], 0, 0, 0);
                }
                accU[0] = __builtin_amdgcn_mfma_f32_16x16x32_bf16(
                    aF[4], bL[0], accU[0], 0, 0, 0);
                accU[1] = __builtin_amdgcn_mfma_f32_16x16x32_bf16(
                    aF[4], bL[1], accU[1], 0, 0, 0);
            }
        }

        float contrib = 0.f;
        #pragma unroll
        for (int nf = 0; nf < 2; ++nf) {
            int c = cbase + nf * 16 + cl;
            float wl  = W2l[c] * (1.0f / 65.0f);
            float w2  = W2r[c];
            float uc  = __shfl(accU[nf][1], cl, 64) + b1[c];
            float ps = 0.f;
            #pragma unroll
            for (int m = 0; m < 4; ++m)
                #pragma unroll
                for (int v = 0; v < 4; ++v)
                    ps += fmaxf(acc[m][nf][v] + uc, 0.f);
            {
                float hh = fmaxf(acc[4][nf][0] + uc, 0.f);
                ps += (g == 0) ? hh : 0.f;
            }
            contrib += wl * ps;
            if (g == 0) {
                float h0 = fmaxf(acc[0][nf][0] + uc, 0.f);
                contrib += w2 * h0;
            }
        }
        #pragma unroll
        for (int mask = 1; mask < 64; mask <<= 1)
            contrib += __shfl_xor(contrib, mask, 64);
        if (lane == 0) atomicAdd(&dout[b], contrib);
    }
}

// ---------------------------------------------------------------------------
extern "C" void kernel_launch(void* const* d_in, const int* in_sizes, int n_in,
                              void* d_out, int out_size, void* d_ws, size_t ws_size,
                              hipStream_t stream) {
    const float* inputs  = (const float*)d_in[0];
    const float* coords  = (const float*)d_in[1];
    const float* targets = (const float*)d_in[2];
    const int*   lens    = (const int*)d_in[3];
    const float* W1l     = (const float*)d_in[4];
    const float* W1r     = (const float*)d_in[5];
    const float* b1      = (const float*)d_in[6];
    const float* W2l     = (const float*)d_in[7];
    const float* W2r     = (const float*)d_in[8];
    const float* b2      = (const float*)d_in[9];
    float* dout = (float*)d_out;

    unsigned short* Wb = (unsigned short*)d_ws;   // 512 KiB, fragment-major
    const size_t needed = 512 * 1024 + (size_t)NBATCH * TILE_SHORTS * 2;

    convw_kernel<<<dim3(2 * HDIM * FDIM / (256 * 8)), dim3(256), 0, stream>>>(
        W1r, W1l, Wb);

    if (ws_size >= needed) {
        unsigned short* tiles = (unsigned short*)((char*)d_ws + 512 * 1024);
        knn_gather_kernel<<<dim3(NBATCH), dim3(512), 0, stream>>>(
            inputs, coords, lens, tiles);
        gemm_kernel<<<dim3(NBATCH), dim3(512), 0, stream>>>(
            tiles, Wb, b1, W2l, W2r, b2, targets, dout);
    } else {
        fused_kernel<<<dim3(NBATCH), dim3(512), 0, stream>>>(
            inputs, coords, targets, lens, Wb, b1, W2l, W2r, b2, dout);
    }
}

// Round 9
// 62.588 us; speedup vs baseline: 2.3726x; 1.1971x over previous
//
#include <hip/hip_runtime.h>
#include <hip/hip_bf16.h>
#include <stdint.h>

typedef __attribute__((ext_vector_type(8))) __bf16 bf16x8;
typedef __attribute__((ext_vector_type(4))) float f32x4;
typedef __attribute__((ext_vector_type(2))) float f32x2;

// Problem constants (B=1024, L=512, F=256, H=512, K=64)
#define NBATCH 1024
#define SEQL   512
#define FDIM   256
#define HDIM   512
#define KNN    64
#define NODES  65
#define ROWSTR 512           // bytes per A-tile row (256 bf16)

__device__ __forceinline__ unsigned short f32_bf16(float f) {
    unsigned int u = __float_as_uint(f);
    unsigned int r = u + 0x7FFFu + ((u >> 16) & 1u);
    return (unsigned short)(r >> 16);
}

// ---------------------------------------------------------------------------
// Kernel 1: convert W1r/W1l to bf16 in MFMA-fragment-major layout (round-3,
// validated): chunk t = ((mat*32 + cb16)*8 + kidx)*64 + lane, 16 B per chunk.
// A wave's B-fragment load is then one contiguous 1KB segment.
// ---------------------------------------------------------------------------
__global__ __launch_bounds__(256) void convw_kernel(
    const float* __restrict__ W1r, const float* __restrict__ W1l,
    unsigned short* __restrict__ Wb)
{
    int i = blockIdx.x * 256 + threadIdx.x;   // 0..32767, one 16B output chunk
    int f = i * 8;                            // first source float in [W1r;W1l]
    int row = f >> 8;                         // 0..1023 (concat row)
    int col = f & 255;                        // multiple of 8
    int mat = row >> 9;
    int r   = row & 511;
    int j   = col >> 3;                       // 0..31
    int g   = j & 3, kidx = j >> 2;
    int cl  = r & 15, cb16 = r >> 4;
    int lane = g * 16 + cl;

    const float* src = (mat ? W1l : W1r) + (size_t)r * FDIM + col;
    float4 a = *reinterpret_cast<const float4*>(src);
    float4 c = *reinterpret_cast<const float4*>(src + 4);
    uint4 t;
    t.x = (unsigned)f32_bf16(a.x) | ((unsigned)f32_bf16(a.y) << 16);
    t.y = (unsigned)f32_bf16(a.z) | ((unsigned)f32_bf16(a.w) << 16);
    t.z = (unsigned)f32_bf16(c.x) | ((unsigned)f32_bf16(c.y) << 16);
    t.w = (unsigned)f32_bf16(c.z) | ((unsigned)f32_bf16(c.w) << 16);

    size_t tchunk = (size_t)((mat * 32 + cb16) * 8 + kidx) * 64 + lane;
    *reinterpret_cast<uint4*>(Wb + tchunk * 8) = t;
}

// ---------------------------------------------------------------------------
// Kernel 2 (fused, one 512-thread block per batch) — round-5 champion.
// Phases: bitonic top-64 -> float4 gather into swizzled bf16 LDS A-tile
// (rows 0..64, row 65 = aggr1) -> per-wave register-B GEMM (fragment-major
// coalesced Wb) -> fused epilogue.
// Change this round: ping-pong key buffer in the cross-wave sort stages ->
// ONE barrier per LDS stage instead of two (6 barriers saved per block).
// ---------------------------------------------------------------------------
__global__ __launch_bounds__(512, 4) void fused_kernel(
    const float* __restrict__ inputs,   // [B,L,F]
    const float* __restrict__ coords,   // [B,L,2]
    const float* __restrict__ targets,  // [B,L,1]
    const int*   __restrict__ lens,     // [B]
    const unsigned short* __restrict__ Wb, // fragment-major, 512 KiB
    const float* __restrict__ b1,       // [H]
    const float* __restrict__ W2l,      // [H]
    const float* __restrict__ W2r,      // [H]
    const float* __restrict__ b2,       // [1]
    float* __restrict__ dout)           // [2048]
{
    __shared__ unsigned long long keys[2][512];               // 8 KiB, ping-pong
    __shared__ int idxs[KNN];
    __shared__ __align__(16) float4 part[8][64];              // 8 KiB
    __shared__ __align__(16) unsigned short ldsA[66 * FDIM];  // 33 KiB, swizzled

    const int b   = blockIdx.x;
    const int tid = threadIdx.x;
    const float* cb = coords + (size_t)b * (SEQL * 2);
    const float qx = cb[0], qy = cb[1];
    const int len = lens[b];

    // ---- phase 1: keys + bitonic sort (ascending), ping-pong LDS stages ----
    unsigned long long key;
    if (tid < SEQL - 1 && tid < len - 1) {
        f32x2 c2 = __builtin_nontemporal_load(
            reinterpret_cast<const f32x2*>(cb + 2 * (tid + 1)));
        float dx = c2[0] - qx;
        float dy = c2[1] - qy;
        float d2 = dx * dx + dy * dy;
        key = ((unsigned long long)__float_as_uint(d2) << 32) | (unsigned int)tid;
    } else {
        key = ~0ull;
    }

    int pp = 0;
    for (int k = 2; k <= 512; k <<= 1) {
        for (int j = k >> 1; j >= 64; j >>= 1) {          // cross-wave via LDS
            keys[pp][tid] = key;
            __syncthreads();
            unsigned long long other = keys[pp][tid ^ j];
            pp ^= 1;                                      // next stage: other buf
            bool takemin = (((tid & j) == 0) == ((tid & k) == 0));
            key = (takemin == (key < other)) ? key : other;
        }
        for (int j = ((k >> 1) > 32 ? 32 : (k >> 1)); j >= 1; j >>= 1) {  // in-wave
            unsigned long long other = __shfl_xor(key, j, 64);
            bool takemin = (((tid & j) == 0) == ((tid & k) == 0));
            key = (takemin == (key < other)) ? key : other;
        }
    }

    if (tid < KNN) idxs[tid] = (int)(unsigned int)(key & 0xffffffffull);
    if (tid == 0) {
        dout[b] = b2[0];                                  // bias init; epilogue accumulates
        dout[NBATCH + b] = targets[(size_t)b * SEQL];     // y head
    }
    __syncthreads();

    const int c4 = tid & 63;          // float4 column 0..63
    const int g0 = tid >> 6;          // row phase 0..7

#define STROW(row, v) do {                                                     \
    int off_ = (row) * ROWSTR + c4 * 8; off_ ^= ((row) & 7) << 4;              \
    uint2 pk_;                                                                 \
    pk_.x = (unsigned)f32_bf16((v)[0]) | ((unsigned)f32_bf16((v)[1]) << 16);   \
    pk_.y = (unsigned)f32_bf16((v)[2]) | ((unsigned)f32_bf16((v)[3]) << 16);   \
    *reinterpret_cast<uint2*>(reinterpret_cast<char*>(ldsA) + off_) = pk_;     \
} while (0)

    // ---- phase 2: nt gather, rows r = g0+8q (+row 64 by g0==0), 9-deep ILP --
    {
        const float* xb = inputs + (size_t)b * SEQL * FDIM + c4 * 4;
        int srcs[8];
        #pragma unroll
        for (int q = 0; q < 8; ++q) {
            int r = g0 + q * 8;
            srcs[q] = (r == 0) ? 0 : idxs[r - 1];
        }
        int src8 = idxs[63];                 // only used by g0==0
        f32x4 v[8];
        #pragma unroll
        for (int q = 0; q < 8; ++q)
            v[q] = __builtin_nontemporal_load(
                reinterpret_cast<const f32x4*>(xb + (size_t)srcs[q] * FDIM));
        f32x4 v8;
        if (g0 == 0)
            v8 = __builtin_nontemporal_load(
                reinterpret_cast<const f32x4*>(xb + (size_t)src8 * FDIM));

        float4 sum = {0.f, 0.f, 0.f, 0.f};
        #pragma unroll
        for (int q = 0; q < 8; ++q) {
            int r = g0 + q * 8;
            sum.x += v[q][0]; sum.y += v[q][1]; sum.z += v[q][2]; sum.w += v[q][3];
            STROW(r, v[q]);
        }
        if (g0 == 0) {
            sum.x += v8[0]; sum.y += v8[1]; sum.z += v8[2]; sum.w += v8[3];
            STROW(64, v8);
        }
        part[g0][c4] = sum;
    }
    __syncthreads();
    if (tid < 64) {                              // row 65 = aggr1 (bf16)
        float sx = 0.f, sy = 0.f, sz = 0.f, sw = 0.f;
        #pragma unroll
        for (int q = 0; q < 8; ++q) {
            float4 p = part[q][tid];
            sx += p.x; sy += p.y; sz += p.z; sw += p.w;
        }
        const float inv = 1.0f / 65.0f;
        uint2 pk;
        pk.x = (unsigned)f32_bf16(sx * inv) | ((unsigned)f32_bf16(sy * inv) << 16);
        pk.y = (unsigned)f32_bf16(sz * inv) | ((unsigned)f32_bf16(sw * inv) << 16);
        int off = 65 * ROWSTR + tid * 8; off ^= 0x10;     // (65&7)<<4
        *reinterpret_cast<uint2*>(reinterpret_cast<char*>(ldsA) + off) = pk;
    }
    __syncthreads();
#undef STROW

    // ---- phase 3: GEMM + epilogue, per wave over 2 passes of 32 cols ----
    const int lane = tid & 63;
    const int w    = tid >> 6;
    const int cl   = lane & 15, g = lane >> 4;

    #pragma unroll
    for (int p = 0; p < 2; ++p) {
        const int cbase = w * 64 + p * 32;

        f32x4 acc[5][2], accU[2];
        #pragma unroll
        for (int m = 0; m < 5; ++m) {
            acc[m][0] = f32x4{0.f, 0.f, 0.f, 0.f};
            acc[m][1] = f32x4{0.f, 0.f, 0.f, 0.f};
        }
        accU[0] = f32x4{0.f, 0.f, 0.f, 0.f};
        accU[1] = f32x4{0.f, 0.f, 0.f, 0.f};

        // fragment-major B: block index blkR = cbase/16; bR1 = blkR+1;
        // W1l at block +32. Each load: contiguous 1KB across the wave.
        const int blkR = w * 4 + p * 2;
        const char* base = (const char*)Wb;
        const size_t oR0 = (size_t)(blkR * 8) * 1024 + (size_t)lane * 16;
        const size_t oR1 = oR0 + 8 * 1024;
        const size_t oL0 = oR0 + (size_t)32 * 8 * 1024;
        const size_t oL1 = oL0 + 8 * 1024;

        #pragma unroll
        for (int kc = 0; kc < 4; ++kc) {
            #pragma unroll
            for (int s = 0; s < 2; ++s) {
                const int kb  = kc * 128 + s * 64;        // byte offset of k-slice (A)
                const int kfr = (kc * 2 + s) * 1024;      // fragment-major B offset
                bf16x8 bR[2], bL[2], aF[5];
                bR[0] = *reinterpret_cast<const bf16x8*>(base + oR0 + kfr);
                bR[1] = *reinterpret_cast<const bf16x8*>(base + oR1 + kfr);
                bL[0] = *reinterpret_cast<const bf16x8*>(base + oL0 + kfr);
                bL[1] = *reinterpret_cast<const bf16x8*>(base + oL1 + kfr);
                #pragma unroll
                for (int m = 0; m < 5; ++m) {
                    int row = m * 16 + cl;
                    int off = row * ROWSTR + kb + g * 16;
                    off ^= (row & 7) << 4;
                    aF[m] = *reinterpret_cast<const bf16x8*>(
                        reinterpret_cast<const char*>(ldsA) + off);
                }
                #pragma unroll
                for (int m = 0; m < 5; ++m) {
                    acc[m][0] = __builtin_amdgcn_mfma_f32_16x16x32_bf16(
                        aF[m], bR[0], acc[m][0], 0, 0, 0);
                    acc[m][1] = __builtin_amdgcn_mfma_f32_16x16x32_bf16(
                        aF[m], bR[1], acc[m][1], 0, 0, 0);
                }
                accU[0] = __builtin_amdgcn_mfma_f32_16x16x32_bf16(
                    aF[4], bL[0], accU[0], 0, 0, 0);
                accU[1] = __builtin_amdgcn_mfma_f32_16x16x32_bf16(
                    aF[4], bL[1], accU[1], 0, 0, 0);
            }
        }

        // epilogue (C/D: col=lane&15, row=(lane>>4)*4+reg)
        float contrib = 0.f;
        #pragma unroll
        for (int nf = 0; nf < 2; ++nf) {
            int c = cbase + nf * 16 + cl;
            float wl  = W2l[c] * (1.0f / 65.0f);
            float w2  = W2r[c];
            float uc  = __shfl(accU[nf][1], cl, 64) + b1[c];   // A-row 65 -> C-row 1
            float ps = 0.f;
            #pragma unroll
            for (int m = 0; m < 4; ++m)
                #pragma unroll
                for (int v = 0; v < 4; ++v)
                    ps += fmaxf(acc[m][nf][v] + uc, 0.f);      // rows 0..63
            {
                float hh = fmaxf(acc[4][nf][0] + uc, 0.f);     // row 64 (g==0,v==0 only)
                ps += (g == 0) ? hh : 0.f;
            }
            contrib += wl * ps;
            if (g == 0) {                                       // j==0 head term (row 0)
                float h0 = fmaxf(acc[0][nf][0] + uc, 0.f);
                contrib += w2 * h0;
            }
        }
        #pragma unroll
        for (int mask = 1; mask < 64; mask <<= 1)
            contrib += __shfl_xor(contrib, mask, 64);
        if (lane == 0) atomicAdd(&dout[b], contrib);
    }
}

// ---------------------------------------------------------------------------
extern "C" void kernel_launch(void* const* d_in, const int* in_sizes, int n_in,
                              void* d_out, int out_size, void* d_ws, size_t ws_size,
                              hipStream_t stream) {
    const float* inputs  = (const float*)d_in[0];
    const float* coords  = (const float*)d_in[1];
    const float* targets = (const float*)d_in[2];
    const int*   lens    = (const int*)d_in[3];
    const float* W1l     = (const float*)d_in[4];
    const float* W1r     = (const float*)d_in[5];
    const float* b1      = (const float*)d_in[6];
    const float* W2l     = (const float*)d_in[7];
    const float* W2r     = (const float*)d_in[8];
    const float* b2      = (const float*)d_in[9];
    float* dout = (float*)d_out;

    unsigned short* Wb = (unsigned short*)d_ws;   // 512 KiB, fragment-major

    convw_kernel<<<dim3(2 * HDIM * FDIM / (256 * 8)), dim3(256), 0, stream>>>(
        W1r, W1l, Wb);

    fused_kernel<<<dim3(NBATCH), dim3(512), 0, stream>>>(
        inputs, coords, targets, lens, Wb, b1, W2l, W2r, b2, dout);
}